// Round 2
// baseline (36.897 us; speedup 1.0000x reference)
//
#include <hip/hip_runtime.h>

#define TBLSZ 4096
#define NSIZES 18
#define DIM 256
#define SEQLEN 8192
#define INV19 (1.0f / 19.0f)

// K1: smix[d] = (sum over 18 tables of mixed row) / 19, i.e. the fast-path output.
__global__ void k_smix(const float* __restrict__ tables, float* __restrict__ smix) {
    int d = threadIdx.x; // 256 threads, 1 block
    float s = 0.f;
#pragma unroll
    for (int t = 0; t < NSIZES; ++t)
        s += tables[((size_t)t * (TBLSZ + 1) + TBLSZ) * DIM + d];
    smix[d] = s * INV19;
}

// K2: pure streaming fill — every position gets the all-mixed result.
// No loads/branches in the loop body; stride % 64 == 0 keeps the fragment invariant.
__global__ __launch_bounds__(256) void k_fill(const float* __restrict__ smix,
                                              float4* __restrict__ out, int total_f4) {
    const int t = blockIdx.x * 256 + threadIdx.x;
    const int stride = gridDim.x * 256;              // 2048*256, multiple of 64
    const float4 v = ((const float4*)smix)[t & 63];
#pragma unroll 4
    for (int f = t; f < total_f4; f += stride)
        out[f] = v;
}

// K3: corrections. Each block owns 256 positions; each thread checks one
// position's size-3 window (coalesced). Waves then cooperatively recompute and
// fully overwrite the rare slow rows (W-A-W with K2 via stream order).
__global__ __launch_bounds__(256) void k_correct(
    const int* __restrict__ byte_ids, const float* __restrict__ tables,
    const float* __restrict__ smix, float* __restrict__ out, int npos)
{
    const int lane = threadIdx.x & 63;
    const int posBase = blockIdx.x * 256 + (threadIdx.x >> 6) * 64;
    const int myPos = posBase + lane;

    bool slow = false;
    if (myPos < npos) {
        const int i = myPos & (SEQLEN - 1);
        if (i >= 2) {
            const int* row = byte_ids + (myPos - i);
            const int v0 = row[i], v1 = row[i - 1], v2 = row[i - 2];
            slow = ((unsigned)(v0 - 1) < 4u) & ((unsigned)(v1 - 1) < 4u)
                 & ((unsigned)(v2 - 1) < 4u);
        }
    }
    unsigned long long mask = __ballot(slow);
    if (!mask) return;

    const float4 basev = ((const float4*)smix)[lane];   // already /19

    while (mask) {
        const int b = __ffsll((long long)mask) - 1;
        mask &= mask - 1;
        const int pos = posBase + b;                    // wave-uniform
        const int i = pos & (SEQLEN - 1);
        const int* row = byte_ids + (pos - i);

        float4 acc = {0.f, 0.f, 0.f, 0.f};
        int h = 0, p = 1;
        for (int j = 0; j < 20; ++j) {
            const int q = i - j;
            const int v = (q >= 0) ? row[q] : 0;
            if ((unsigned)(v - 1) >= 4u) break;         // window bad from here on
            h = (h + (v - 1) * p) & (TBLSZ - 1);
            p = (p * 31) & (TBLSZ - 1);
            const int k = j + 1;
            if (k >= 3) {
                const float4* T4 =
                    (const float4*)(tables + (size_t)(k - 3) * (TBLSZ + 1) * DIM);
                const float4 g = T4[(size_t)h * (DIM / 4) + lane];
                const float4 m = T4[(size_t)TBLSZ * (DIM / 4) + lane];
                acc.x += g.x - m.x; acc.y += g.y - m.y;
                acc.z += g.z - m.z; acc.w += g.w - m.w;
            }
        }
        float4 r;
        r.x = basev.x + acc.x * INV19;
        r.y = basev.y + acc.y * INV19;
        r.z = basev.z + acc.z * INV19;
        r.w = basev.w + acc.w * INV19;
        ((float4*)out)[(size_t)pos * (DIM / 4) + lane] = r;
    }
}

extern "C" void kernel_launch(void* const* d_in, const int* in_sizes, int n_in,
                              void* d_out, int out_size, void* d_ws, size_t ws_size,
                              hipStream_t stream) {
    const int*   byte_ids = (const int*)d_in[0];
    const float* tables   = (const float*)d_in[1];
    float* out  = (float*)d_out;
    float* smix = (float*)d_ws;                  // 1 KB scratch
    const int npos = in_sizes[0];                // B*L = 65536
    const int total_f4 = npos * (DIM / 4);

    hipLaunchKernelGGL(k_smix, dim3(1), dim3(256), 0, stream, tables, smix);
    hipLaunchKernelGGL(k_fill, dim3(2048), dim3(256), 0, stream,
                       smix, (float4*)out, total_f4);
    hipLaunchKernelGGL(k_correct, dim3((npos + 255) / 256), dim3(256), 0, stream,
                       byte_ids, tables, smix, out, npos);
}

// Round 3
// 24.536 us; speedup vs baseline: 1.5038x; 1.5038x over previous
//
#include <hip/hip_runtime.h>

#define TBLSZ 4096
#define NSIZES 18
#define DIM 256
#define D4 (DIM / 4)        // float4s per position
#define SEQLEN 8192
#define INV19 (1.0f / 19.0f)
#define CHUNK 64            // positions per chunk (one ballot per chunk)
#define WPC 4               // waves cooperating on one chunk
#define SLICE (CHUNK / WPC) // 16 positions stored per wave

__global__ __launch_bounds__(256) void NGramEmbedding_73718818668652_kernel(
    const int* __restrict__ byte_ids, const float* __restrict__ tables,
    float4* __restrict__ out, int nchunk)
{
    const int lane  = threadIdx.x & 63;
    const int gwave = (blockIdx.x * 256 + threadIdx.x) >> 6;
    const int cid   = gwave / WPC;          // chunk id
    const int sub   = gwave % WPC;          // slice within chunk
    if (cid >= nchunk) return;

    // Per-lane smix fragment (sum of the 18 mixed rows, pre-divided by 19).
    // Mixed rows are ~18 KB total -> L2/L3-hot; independent loads.
    const float4* T4base = (const float4*)tables;
    float4 base = {0.f, 0.f, 0.f, 0.f};
#pragma unroll
    for (int t = 0; t < NSIZES; ++t) {
        float4 m = T4base[((size_t)t * (TBLSZ + 1) + TBLSZ) * D4 + lane];
        base.x += m.x; base.y += m.y; base.z += m.z; base.w += m.w;
    }
    base.x *= INV19; base.y *= INV19; base.z *= INV19; base.w *= INV19;

    const int chunkBase = cid * CHUNK;               // global position base
    const int ibase     = chunkBase & (SEQLEN - 1);  // in-row offset (rows are 64-aligned)
    const int* row      = byte_ids + (chunkBase - ibase);

    // Lane l checks position chunkBase+l: is its size-3 window all-DNA?
    const int i = ibase + lane;
    bool slowb = false;
    if (i >= 2) {
        const int v0 = row[i], v1 = row[i - 1], v2 = row[i - 2];
        slowb = ((unsigned)(v0 - 1) < 4u) & ((unsigned)(v1 - 1) < 4u)
              & ((unsigned)(v2 - 1) < 4u);
    }
    const unsigned long long mask = __ballot(slowb);

    // Stream this wave's 16-position slice.
    const int p0 = sub * SLICE;
    float4* dst = out + (size_t)(chunkBase + p0) * D4 + lane;

    if (((mask >> p0) & 0xFFFFull) == 0) {
        // Pure fast path: 16 back-to-back 1KB stores, no loads, no branches.
#pragma unroll
        for (int p = 0; p < SLICE; ++p)
            dst[(size_t)p * D4] = base;
    } else {
        for (int p = 0; p < SLICE; ++p) {
            float4 r = base;
            if ((mask >> (p0 + p)) & 1ull) {        // wave-uniform, rare
                const int ii = ibase + p0 + p;
                float4 acc = {0.f, 0.f, 0.f, 0.f};
                int h = 0, pw = 1;
                for (int j = 0; j < 20; ++j) {
                    const int q = ii - j;
                    const int v = (q >= 0) ? row[q] : 0;
                    if ((unsigned)(v - 1) >= 4u) break;  // window bad beyond here
                    h  = (h + (v - 1) * pw) & (TBLSZ - 1);
                    pw = (pw * 31) & (TBLSZ - 1);
                    const int k = j + 1;
                    if (k >= 3) {
                        const float4* T4 = T4base + (size_t)(k - 3) * (TBLSZ + 1) * D4;
                        const float4 g = T4[(size_t)h * D4 + lane];
                        const float4 m = T4[(size_t)TBLSZ * D4 + lane];
                        acc.x += g.x - m.x; acc.y += g.y - m.y;
                        acc.z += g.z - m.z; acc.w += g.w - m.w;
                    }
                }
                r.x += acc.x * INV19; r.y += acc.y * INV19;
                r.z += acc.z * INV19; r.w += acc.w * INV19;
            }
            dst[(size_t)p * D4] = r;
        }
    }
}

extern "C" void kernel_launch(void* const* d_in, const int* in_sizes, int n_in,
                              void* d_out, int out_size, void* d_ws, size_t ws_size,
                              hipStream_t stream) {
    const int*   byte_ids = (const int*)d_in[0];
    const float* tables   = (const float*)d_in[1];
    float* out = (float*)d_out;
    const int npos   = in_sizes[0];          // B*L = 65536
    const int nchunk = npos / CHUNK;         // 1024
    const int nblocks = (nchunk * WPC * 64) / 256;  // 1024 blocks (4 waves each)

    hipLaunchKernelGGL(NGramEmbedding_73718818668652_kernel,
                       dim3(nblocks), dim3(256), 0, stream,
                       byte_ids, tables, (float4*)out, nchunk);
}

// Round 4
// 22.081 us; speedup vs baseline: 1.6710x; 1.1112x over previous
//
#include <hip/hip_runtime.h>

#define TBLSZ 4096
#define NSIZES 18
#define DIM 256
#define D4 (DIM / 4)        // float4s per position
#define SEQLEN 8192
#define INV19 (1.0f / 19.0f)
#define CHUNK 64            // positions per block
#define WPC 4               // waves per block
#define SLICE (CHUNK / WPC) // 16 positions stored per wave

typedef float f32x4 __attribute__((ext_vector_type(4)));

__global__ __launch_bounds__(256) void NGramEmbedding_73718818668652_kernel(
    const int* __restrict__ byte_ids, const float* __restrict__ tables,
    f32x4* __restrict__ out, int nchunk)
{
    __shared__ f32x4 s_part[WPC][64];

    const int lane = threadIdx.x & 63;
    const int wv   = threadIdx.x >> 6;
    const int cid  = blockIdx.x;
    if (cid >= nchunk) return;

    const f32x4* T4base = (const f32x4*)tables;

    // Phase 1: cooperative smix — each wave sums 4-5 mixed rows, LDS-reduce.
    // Read volume: 18 KB per BLOCK (18 MB total), not per wave (was 72 MB).
    f32x4 part = {0.f, 0.f, 0.f, 0.f};
    for (int t = wv; t < NSIZES; t += WPC)
        part += T4base[((size_t)t * (TBLSZ + 1) + TBLSZ) * D4 + lane];
    s_part[wv][lane] = part;
    __syncthreads();
    f32x4 base = (s_part[0][lane] + s_part[1][lane] +
                  s_part[2][lane] + s_part[3][lane]) * INV19;

    const int chunkBase = cid * CHUNK;
    const int ibase     = chunkBase & (SEQLEN - 1);  // rows are 64-aligned
    const int* row      = byte_ids + (chunkBase - ibase);

    // Lane l checks position chunkBase+l: size-3 window all-DNA?
    const int i = ibase + lane;
    bool slowb = false;
    if (i >= 2) {
        const int v0 = row[i], v1 = row[i - 1], v2 = row[i - 2];
        slowb = ((unsigned)(v0 - 1) < 4u) & ((unsigned)(v1 - 1) < 4u)
              & ((unsigned)(v2 - 1) < 4u);
    }
    const unsigned long long mask = __ballot(slowb);

    const int p0 = wv * SLICE;
    f32x4* dst = out + (size_t)(chunkBase + p0) * D4 + lane;

    if (((mask >> p0) & 0xFFFFull) == 0) {
        // Pure fast path: 16 back-to-back nontemporal 1KB stores.
#pragma unroll
        for (int p = 0; p < SLICE; ++p)
            __builtin_nontemporal_store(base, &dst[(size_t)p * D4]);
    } else {
        for (int p = 0; p < SLICE; ++p) {
            f32x4 r = base;
            if ((mask >> (p0 + p)) & 1ull) {        // wave-uniform, rare
                const int ii = ibase + p0 + p;
                f32x4 acc = {0.f, 0.f, 0.f, 0.f};
                int h = 0, pw = 1;
                for (int j = 0; j < 20; ++j) {
                    const int q = ii - j;
                    const int v = (q >= 0) ? row[q] : 0;
                    if ((unsigned)(v - 1) >= 4u) break;  // window bad beyond here
                    h  = (h + (v - 1) * pw) & (TBLSZ - 1);
                    pw = (pw * 31) & (TBLSZ - 1);
                    const int k = j + 1;
                    if (k >= 3) {
                        const f32x4* T4 = T4base + (size_t)(k - 3) * (TBLSZ + 1) * D4;
                        const f32x4 g = T4[(size_t)h * D4 + lane];
                        const f32x4 m = T4[(size_t)TBLSZ * D4 + lane];
                        acc += g - m;
                    }
                }
                r += acc * INV19;
            }
            __builtin_nontemporal_store(r, &dst[(size_t)p * D4]);
        }
    }
}

extern "C" void kernel_launch(void* const* d_in, const int* in_sizes, int n_in,
                              void* d_out, int out_size, void* d_ws, size_t ws_size,
                              hipStream_t stream) {
    const int*   byte_ids = (const int*)d_in[0];
    const float* tables   = (const float*)d_in[1];
    float* out = (float*)d_out;
    const int npos   = in_sizes[0];          // B*L = 65536
    const int nchunk = npos / CHUNK;         // 1024

    hipLaunchKernelGGL(NGramEmbedding_73718818668652_kernel,
                       dim3(nchunk), dim3(256), 0, stream,
                       byte_ids, tables, (f32x4*)out, nchunk);
}